// Round 1
// baseline (163.288 us; speedup 1.0000x reference)
//
#include <hip/hip_runtime.h>
#include <hip/hip_bf16.h>

#define BB 2
#define CC 4
#define KK 32
#define HHH 96
#define WWW 96
#define DDD 64
#define NN (DDD * DDD * DDD)   /* 262144 */
#define HWSZ (HHH * WWW)       /* 9216 */

// ---------------------------------------------------------------------------
// Kernel 1: transpose heatmaps (B,C,K,H,W) -> (B,C,H,W,K) so the K dimension
// is contiguous (one bilinear corner = 128 B contiguous = 8x float4 loads).
// ---------------------------------------------------------------------------
__global__ __launch_bounds__(256) void hm_transpose(const float* __restrict__ in,
                                                    float* __restrict__ out) {
  __shared__ float tile[KK][64 + 1];   // +1 pad: conflict-free transpose read
  const int bc  = blockIdx.y;          // 0..B*C-1
  const int hw0 = blockIdx.x * 64;
  const int t   = threadIdx.x;

  const float* src = in + (size_t)bc * KK * HWSZ;
  const int lhw = t & 63, lk0 = t >> 6;      // wave covers 64 consecutive hw
#pragma unroll
  for (int i = 0; i < 8; ++i) {
    const int k = lk0 + i * 4;
    tile[k][lhw] = src[(size_t)k * HWSZ + hw0 + lhw];   // coalesced 256B/wave
  }
  __syncthreads();

  float* dst = out + ((size_t)bc * HWSZ + hw0) * KK;
  const int lk = t & 31, lh0 = t >> 5;
#pragma unroll
  for (int i = 0; i < 8; ++i) {
    const int h = lh0 + i * 8;
    dst[(size_t)h * KK + lk] = tile[lk][h];             // coalesced 256B/wave
  }
}

// ---------------------------------------------------------------------------
// Kernel 2: unprojection. One thread = one (b, voxel); all K=32 joints kept
// in registers as float4 acc[8]. TRANSPOSED=1 reads (B,C,H,W,K) from ws,
// TRANSPOSED=0 is a correctness fallback reading the native layout.
// ---------------------------------------------------------------------------
template <int TRANSPOSED>
__global__ __launch_bounds__(256) void unproject(
    const float* __restrict__ hm,     // transposed (B,C,H,W,K) or native
    const float* __restrict__ Pm,     // (B,C,3,4)
    const float* __restrict__ coords, // (B,N,3)
    const float* __restrict__ conf,   // (B,C,K)
    float* __restrict__ out) {        // (B,K,N)
  __shared__ float sP[CC * 12];
  __shared__ float sConf[CC * KK];

  const int t   = threadIdx.x;
  const int gid = blockIdx.x * 256 + t;
  const int b   = gid >> 18;           // N = 2^18, uniform per block
  const int n   = gid & (NN - 1);

  if (t < CC * 12) sP[t] = Pm[b * CC * 12 + t];
  if (t < KK) {
    const float c0 = conf[(b * CC + 0) * KK + t];
    const float c1 = conf[(b * CC + 1) * KK + t];
    const float c2 = conf[(b * CC + 2) * KK + t];
    const float c3 = conf[(b * CC + 3) * KK + t];
    const float s  = c0 + c1 + c2 + c3;
    sConf[0 * KK + t] = c0 / s;
    sConf[1 * KK + t] = c1 / s;
    sConf[2 * KK + t] = c2 / s;
    sConf[3 * KK + t] = c3 / s;
  }
  __syncthreads();

  const float x = coords[(size_t)gid * 3 + 0];
  const float y = coords[(size_t)gid * 3 + 1];
  const float z = coords[(size_t)gid * 3 + 2];

  float4 acc[8];
#pragma unroll
  for (int i = 0; i < 8; ++i) acc[i] = make_float4(0.f, 0.f, 0.f, 0.f);

  // ix = (gx+1)*0.5*(W-1) with gx = 2*(u/H - 0.5)  =>  ix = u*(W-1)/H
  const float sxc = (float)(WWW - 1) / (float)HHH;
  const float syc = (float)(HHH - 1) / (float)WWW;

#pragma unroll
  for (int c = 0; c < CC; ++c) {
    const float* P = &sP[c * 12];
    const float pz = P[8] * x + P[9] * y + P[10] * z + P[11];
    if (pz > 0.0f) {   // z<=0 voxels are zeroed in the reference -> skip camera
      const float px = P[0] * x + P[1] * y + P[2] * z + P[3];
      const float py = P[4] * x + P[5] * y + P[6] * z + P[7];
      const float u = px / pz, v = py / pz;
      const float ix = u * sxc, iy = v * syc;
      const float x0f = floorf(ix), y0f = floorf(iy);
      const float x1f = x0f + 1.0f, y1f = y0f + 1.0f;
      const float wx1 = ix - x0f, wx0 = 1.0f - wx1;
      const float wy1 = iy - y0f, wy0 = 1.0f - wy1;
      const float ibx0 = (x0f >= 0.f && x0f <= (float)(WWW - 1)) ? 1.f : 0.f;
      const float ibx1 = (x1f >= 0.f && x1f <= (float)(WWW - 1)) ? 1.f : 0.f;
      const float iby0 = (y0f >= 0.f && y0f <= (float)(HHH - 1)) ? 1.f : 0.f;
      const float iby1 = (y1f >= 0.f && y1f <= (float)(HHH - 1)) ? 1.f : 0.f;
      const float w00 = wx0 * wy0 * ibx0 * iby0;
      const float w01 = wx1 * wy0 * ibx1 * iby0;
      const float w10 = wx0 * wy1 * ibx0 * iby1;
      const float w11 = wx1 * wy1 * ibx1 * iby1;
      const int x0i = (int)fminf(fmaxf(x0f, 0.f), (float)(WWW - 1));
      const int x1i = (int)fminf(fmaxf(x1f, 0.f), (float)(WWW - 1));
      const int y0i = (int)fminf(fmaxf(y0f, 0.f), (float)(HHH - 1));
      const int y1i = (int)fminf(fmaxf(y1f, 0.f), (float)(HHH - 1));

      const float* cf = &sConf[c * KK];

      if (TRANSPOSED) {
        const size_t slice = (size_t)(b * CC + c) * HWSZ;
        const float4* b00 = (const float4*)(hm + (slice + y0i * WWW + x0i) * KK);
        const float4* b01 = (const float4*)(hm + (slice + y0i * WWW + x1i) * KK);
        const float4* b10 = (const float4*)(hm + (slice + y1i * WWW + x0i) * KK);
        const float4* b11 = (const float4*)(hm + (slice + y1i * WWW + x1i) * KK);
        const float4* cf4 = (const float4*)cf;
#pragma unroll
        for (int kk = 0; kk < 8; ++kk) {
          const float4 g00 = b00[kk], g01 = b01[kk];
          const float4 g10 = b10[kk], g11 = b11[kk];
          const float4 w   = cf4[kk];
          acc[kk].x += (g00.x * w00 + g01.x * w01 + g10.x * w10 + g11.x * w11) * w.x;
          acc[kk].y += (g00.y * w00 + g01.y * w01 + g10.y * w10 + g11.y * w11) * w.y;
          acc[kk].z += (g00.z * w00 + g01.z * w01 + g10.z * w10 + g11.z * w11) * w.z;
          acc[kk].w += (g00.w * w00 + g01.w * w01 + g10.w * w10 + g11.w * w11) * w.w;
        }
      } else {
        // fallback: native (B,C,K,H,W) layout, strided k loads
        const float* base = hm + (size_t)(b * CC + c) * KK * HWSZ;
        const int i00 = y0i * WWW + x0i, i01 = y0i * WWW + x1i;
        const int i10 = y1i * WWW + x0i, i11 = y1i * WWW + x1i;
#pragma unroll
        for (int kk = 0; kk < 8; ++kk) {
#pragma unroll
          for (int j = 0; j < 4; ++j) {
            const int k = kk * 4 + j;
            const float* hk = base + (size_t)k * HWSZ;
            const float val = hk[i00] * w00 + hk[i01] * w01 +
                              hk[i10] * w10 + hk[i11] * w11;
            float* a = (float*)&acc[kk];
            a[j] += val * cf[k];
          }
        }
      }
    }
  }

  float* ob = out + (size_t)b * KK * NN + n;
#pragma unroll
  for (int kk = 0; kk < 8; ++kk) {
    ob[(size_t)(kk * 4 + 0) * NN] = acc[kk].x;   // coalesced across lanes
    ob[(size_t)(kk * 4 + 1) * NN] = acc[kk].y;
    ob[(size_t)(kk * 4 + 2) * NN] = acc[kk].z;
    ob[(size_t)(kk * 4 + 3) * NN] = acc[kk].w;
  }
}

extern "C" void kernel_launch(void* const* d_in, const int* in_sizes, int n_in,
                              void* d_out, int out_size, void* d_ws, size_t ws_size,
                              hipStream_t stream) {
  const float* heatmaps = (const float*)d_in[0];  // (B,C,K,H,W)
  const float* Pm       = (const float*)d_in[1];  // (B,C,3,4)
  const float* coords   = (const float*)d_in[2];  // (B,D,D,D,3)
  const float* conf     = (const float*)d_in[3];  // (B,C,K)
  float* out            = (float*)d_out;          // (B,K,D,D,D)

  const size_t hmT_bytes = (size_t)BB * CC * HWSZ * KK * sizeof(float); // 9.4 MB
  const int grid_main = (BB * NN) / 256;          // 2048 blocks

  if (ws_size >= hmT_bytes) {
    float* hmT = (float*)d_ws;
    dim3 tg(HWSZ / 64, BB * CC);                  // (144, 8)
    hm_transpose<<<tg, 256, 0, stream>>>(heatmaps, hmT);
    unproject<1><<<grid_main, 256, 0, stream>>>(hmT, Pm, coords, conf, out);
  } else {
    unproject<0><<<grid_main, 256, 0, stream>>>(heatmaps, Pm, coords, conf, out);
  }
}

// Round 2
// 129.461 us; speedup vs baseline: 1.2613x; 1.2613x over previous
//
#include <hip/hip_runtime.h>
#include <hip/hip_bf16.h>

#define BB 2
#define CC 4
#define KK 32
#define HHH 96
#define WWW 96
#define DDD 64
#define NN (DDD * DDD * DDD)   /* 262144 */
#define HWSZ (HHH * WWW)       /* 9216 */

// ---------------------------------------------------------------------------
// Kernel 1: transpose heatmaps (B,C,K,H,W) -> (B,C,H,W,K). One bilinear
// corner's 32-k run is then a contiguous, 128B-aligned 128-byte line.
// ---------------------------------------------------------------------------
__global__ __launch_bounds__(256) void hm_transpose(const float* __restrict__ in,
                                                    float* __restrict__ out) {
  __shared__ float tile[KK][64 + 1];
  const int bc  = blockIdx.y;          // 0..B*C-1
  const int hw0 = blockIdx.x * 64;
  const int t   = threadIdx.x;

  const float* src = in + (size_t)bc * KK * HWSZ;
  const int lhw = t & 63, lk0 = t >> 6;
#pragma unroll
  for (int i = 0; i < 8; ++i) {
    const int k = lk0 + i * 4;
    tile[k][lhw] = src[(size_t)k * HWSZ + hw0 + lhw];   // coalesced 256B/wave
  }
  __syncthreads();

  float* dst = out + ((size_t)bc * HWSZ + hw0) * KK;
  const int lk = t & 31, lh0 = t >> 5;
#pragma unroll
  for (int i = 0; i < 8; ++i) {
    const int h = lh0 + i * 8;
    dst[(size_t)h * KK + lk] = tile[lk][h];             // coalesced 256B/wave
  }
}

// ---------------------------------------------------------------------------
// Kernel 2 (v2): cooperative K-gather. 8 consecutive lanes = 1 voxel; lane j
// owns k-chunk j (4 k's). Each bilinear corner = one 128B line shared by the
// 8 lanes -> 8 transactions per wave gather instr (was 64). Output is
// re-transposed through LDS so stores are 128B-coalesced.
// ---------------------------------------------------------------------------
__global__ __launch_bounds__(256) void unproject2(
    const float* __restrict__ hmT,    // (B,C,H,W,K)
    const float* __restrict__ Pm,     // (B,C,3,4)
    const float* __restrict__ coords, // (B,N,3)
    const float* __restrict__ conf,   // (B,C,K)
    float* __restrict__ out) {        // (B,K,N)
  __shared__ float sP[CC * 12];
  __shared__ float sConf[CC][KK];
  __shared__ float sXYZ[32 * 3];
  __shared__ float vtile[32][KK + 1];

  const int t     = threadIdx.x;
  const int vbase = blockIdx.x * 32;      // global voxel index base (b*N + n)
  const int b     = vbase >> 18;          // uniform per block (32 | 2^18)
  const int nbase = vbase & (NN - 1);

  if (t < CC * 12) sP[t] = Pm[b * CC * 12 + t];
  if (t < 96)      sXYZ[t] = coords[(size_t)vbase * 3 + t];
  if (t < KK) {
    const float c0 = conf[(b * CC + 0) * KK + t];
    const float c1 = conf[(b * CC + 1) * KK + t];
    const float c2 = conf[(b * CC + 2) * KK + t];
    const float c3 = conf[(b * CC + 3) * KK + t];
    const float s  = c0 + c1 + c2 + c3;
    sConf[0][t] = c0 / s;
    sConf[1][t] = c1 / s;
    sConf[2][t] = c2 / s;
    sConf[3][t] = c3 / s;
  }
  __syncthreads();

  const int v = t >> 3;                   // voxel within block (0..31)
  const int j = t & 7;                    // k-chunk (k = 4j..4j+3)
  const float x = sXYZ[v * 3 + 0];
  const float y = sXYZ[v * 3 + 1];
  const float z = sXYZ[v * 3 + 2];

  float4 acc = make_float4(0.f, 0.f, 0.f, 0.f);

  // ix = (gx+1)*0.5*(W-1) with gx = 2*(u/H - 0.5)  =>  ix = u*(W-1)/H
  const float sxc = (float)(WWW - 1) / (float)HHH;
  const float syc = (float)(HHH - 1) / (float)WWW;

#pragma unroll
  for (int c = 0; c < CC; ++c) {
    const float* P = &sP[c * 12];
    const float pz = P[8] * x + P[9] * y + P[10] * z + P[11];
    if (pz > 0.0f) {  // z<=0 voxels zeroed in reference -> skip camera
      const float px = P[0] * x + P[1] * y + P[2] * z + P[3];
      const float py = P[4] * x + P[5] * y + P[6] * z + P[7];
      const float u = px / pz, v2 = py / pz;
      const float ix = u * sxc, iy = v2 * syc;
      const float x0f = floorf(ix), y0f = floorf(iy);
      const float x1f = x0f + 1.0f, y1f = y0f + 1.0f;
      const float wx1 = ix - x0f, wx0 = 1.0f - wx1;
      const float wy1 = iy - y0f, wy0 = 1.0f - wy1;
      const float ibx0 = (x0f >= 0.f && x0f <= (float)(WWW - 1)) ? 1.f : 0.f;
      const float ibx1 = (x1f >= 0.f && x1f <= (float)(WWW - 1)) ? 1.f : 0.f;
      const float iby0 = (y0f >= 0.f && y0f <= (float)(HHH - 1)) ? 1.f : 0.f;
      const float iby1 = (y1f >= 0.f && y1f <= (float)(HHH - 1)) ? 1.f : 0.f;
      const float w00 = wx0 * wy0 * ibx0 * iby0;
      const float w01 = wx1 * wy0 * ibx1 * iby0;
      const float w10 = wx0 * wy1 * ibx0 * iby1;
      const float w11 = wx1 * wy1 * ibx1 * iby1;
      const int x0i = (int)fminf(fmaxf(x0f, 0.f), (float)(WWW - 1));
      const int x1i = (int)fminf(fmaxf(x1f, 0.f), (float)(WWW - 1));
      const int y0i = (int)fminf(fmaxf(y0f, 0.f), (float)(HHH - 1));
      const int y1i = (int)fminf(fmaxf(y1f, 0.f), (float)(HHH - 1));

      // lane j reads its 16B chunk of each corner's 128B k-run
      const float* base = hmT + (size_t)(b * CC + c) * HWSZ * KK + j * 4;
      const float4 g00 = *(const float4*)(base + (y0i * WWW + x0i) * KK);
      const float4 g01 = *(const float4*)(base + (y0i * WWW + x1i) * KK);
      const float4 g10 = *(const float4*)(base + (y1i * WWW + x0i) * KK);
      const float4 g11 = *(const float4*)(base + (y1i * WWW + x1i) * KK);
      const float4 w   = ((const float4*)sConf[c])[j];
      acc.x += (g00.x * w00 + g01.x * w01 + g10.x * w10 + g11.x * w11) * w.x;
      acc.y += (g00.y * w00 + g01.y * w01 + g10.y * w10 + g11.y * w11) * w.y;
      acc.z += (g00.z * w00 + g01.z * w01 + g10.z * w10 + g11.z * w11) * w.z;
      acc.w += (g00.w * w00 + g01.w * w01 + g10.w * w10 + g11.w * w11) * w.w;
    }
  }

  // transpose 32x32 result tile through LDS for coalesced stores
  vtile[v][j * 4 + 0] = acc.x;
  vtile[v][j * 4 + 1] = acc.y;
  vtile[v][j * 4 + 2] = acc.z;
  vtile[v][j * 4 + 3] = acc.w;
  __syncthreads();

  float* ob = out + (size_t)b * KK * NN + nbase;
#pragma unroll
  for (int q = 0; q < 4; ++q) {
    const int idx = t + q * 256;
    const int k   = idx >> 5;
    const int n0  = idx & 31;
    ob[(size_t)k * NN + n0] = vtile[n0][k];   // 64 lanes -> 2x128B segments
  }
}

// ---------------------------------------------------------------------------
// Fallback (native layout, no workspace): one thread = one voxel, strided k.
// ---------------------------------------------------------------------------
__global__ __launch_bounds__(256) void unproject_native(
    const float* __restrict__ hm, const float* __restrict__ Pm,
    const float* __restrict__ coords, const float* __restrict__ conf,
    float* __restrict__ out) {
  __shared__ float sP[CC * 12];
  __shared__ float sConf[CC * KK];
  const int t   = threadIdx.x;
  const int gid = blockIdx.x * 256 + t;
  const int b   = gid >> 18;
  const int n   = gid & (NN - 1);
  if (t < CC * 12) sP[t] = Pm[b * CC * 12 + t];
  if (t < KK) {
    const float c0 = conf[(b * CC + 0) * KK + t];
    const float c1 = conf[(b * CC + 1) * KK + t];
    const float c2 = conf[(b * CC + 2) * KK + t];
    const float c3 = conf[(b * CC + 3) * KK + t];
    const float s  = c0 + c1 + c2 + c3;
    sConf[0 * KK + t] = c0 / s; sConf[1 * KK + t] = c1 / s;
    sConf[2 * KK + t] = c2 / s; sConf[3 * KK + t] = c3 / s;
  }
  __syncthreads();
  const float x = coords[(size_t)gid * 3 + 0];
  const float y = coords[(size_t)gid * 3 + 1];
  const float z = coords[(size_t)gid * 3 + 2];
  float accs[KK];
#pragma unroll
  for (int k = 0; k < KK; ++k) accs[k] = 0.f;
  const float sxc = (float)(WWW - 1) / (float)HHH;
  const float syc = (float)(HHH - 1) / (float)WWW;
#pragma unroll
  for (int c = 0; c < CC; ++c) {
    const float* P = &sP[c * 12];
    const float pz = P[8] * x + P[9] * y + P[10] * z + P[11];
    if (pz > 0.0f) {
      const float px = P[0] * x + P[1] * y + P[2] * z + P[3];
      const float py = P[4] * x + P[5] * y + P[6] * z + P[7];
      const float u = px / pz, v2 = py / pz;
      const float ix = u * sxc, iy = v2 * syc;
      const float x0f = floorf(ix), y0f = floorf(iy);
      const float x1f = x0f + 1.0f, y1f = y0f + 1.0f;
      const float wx1 = ix - x0f, wx0 = 1.0f - wx1;
      const float wy1 = iy - y0f, wy0 = 1.0f - wy1;
      const float ibx0 = (x0f >= 0.f && x0f <= (float)(WWW - 1)) ? 1.f : 0.f;
      const float ibx1 = (x1f >= 0.f && x1f <= (float)(WWW - 1)) ? 1.f : 0.f;
      const float iby0 = (y0f >= 0.f && y0f <= (float)(HHH - 1)) ? 1.f : 0.f;
      const float iby1 = (y1f >= 0.f && y1f <= (float)(HHH - 1)) ? 1.f : 0.f;
      const float w00 = wx0 * wy0 * ibx0 * iby0;
      const float w01 = wx1 * wy0 * ibx1 * iby0;
      const float w10 = wx0 * wy1 * ibx0 * iby1;
      const float w11 = wx1 * wy1 * ibx1 * iby1;
      const int x0i = (int)fminf(fmaxf(x0f, 0.f), (float)(WWW - 1));
      const int x1i = (int)fminf(fmaxf(x1f, 0.f), (float)(WWW - 1));
      const int y0i = (int)fminf(fmaxf(y0f, 0.f), (float)(HHH - 1));
      const int y1i = (int)fminf(fmaxf(y1f, 0.f), (float)(HHH - 1));
      const float* bse = hm + (size_t)(b * CC + c) * KK * HWSZ;
      const int i00 = y0i * WWW + x0i, i01 = y0i * WWW + x1i;
      const int i10 = y1i * WWW + x0i, i11 = y1i * WWW + x1i;
#pragma unroll
      for (int k = 0; k < KK; ++k) {
        const float* hk = bse + (size_t)k * HWSZ;
        accs[k] += (hk[i00] * w00 + hk[i01] * w01 +
                    hk[i10] * w10 + hk[i11] * w11) * sConf[c * KK + k];
      }
    }
  }
  float* ob = out + (size_t)b * KK * NN + n;
#pragma unroll
  for (int k = 0; k < KK; ++k) ob[(size_t)k * NN] = accs[k];
}

extern "C" void kernel_launch(void* const* d_in, const int* in_sizes, int n_in,
                              void* d_out, int out_size, void* d_ws, size_t ws_size,
                              hipStream_t stream) {
  const float* heatmaps = (const float*)d_in[0];  // (B,C,K,H,W)
  const float* Pm       = (const float*)d_in[1];  // (B,C,3,4)
  const float* coords   = (const float*)d_in[2];  // (B,D,D,D,3)
  const float* conf     = (const float*)d_in[3];  // (B,C,K)
  float* out            = (float*)d_out;          // (B,K,D,D,D)

  const size_t hmT_bytes = (size_t)BB * CC * HWSZ * KK * sizeof(float); // 9.4 MB

  if (ws_size >= hmT_bytes) {
    float* hmT = (float*)d_ws;
    dim3 tg(HWSZ / 64, BB * CC);                  // (144, 8)
    hm_transpose<<<tg, 256, 0, stream>>>(heatmaps, hmT);
    const int grid = (BB * NN) / 32;              // 16384 blocks, 32 voxels each
    unproject2<<<grid, 256, 0, stream>>>(hmT, Pm, coords, conf, out);
  } else {
    const int grid = (BB * NN) / 256;
    unproject_native<<<grid, 256, 0, stream>>>(heatmaps, Pm, coords, conf, out);
  }
}

// Round 4
// 122.036 us; speedup vs baseline: 1.3380x; 1.0608x over previous
//
#include <hip/hip_runtime.h>
#include <hip/hip_bf16.h>

#define BB 2
#define CC 4
#define KK 32
#define HHH 96
#define WWW 96
#define DDD 64
#define NN (DDD * DDD * DDD)   /* 262144 */
#define HWSZ (HHH * WWW)       /* 9216 */

// ---------------------------------------------------------------------------
// Kernel 1: transpose heatmaps (B,C,K,H,W) -> (B,C,H,W,K). One bilinear
// corner's 32-k run is then a contiguous, 128B-aligned 128-byte line.
// ---------------------------------------------------------------------------
__global__ __launch_bounds__(256) void hm_transpose(const float* __restrict__ in,
                                                    float* __restrict__ out) {
  __shared__ float tile[KK][64 + 1];
  const int bc  = blockIdx.y;          // 0..B*C-1
  const int hw0 = blockIdx.x * 64;
  const int t   = threadIdx.x;

  const float* src = in + (size_t)bc * KK * HWSZ;
  const int lhw = t & 63, lk0 = t >> 6;
#pragma unroll
  for (int i = 0; i < 8; ++i) {
    const int k = lk0 + i * 4;
    tile[k][lhw] = src[(size_t)k * HWSZ + hw0 + lhw];   // coalesced 256B/wave
  }
  __syncthreads();

  float* dst = out + ((size_t)bc * HWSZ + hw0) * KK;
  const int lk = t & 31, lh0 = t >> 5;
#pragma unroll
  for (int i = 0; i < 8; ++i) {
    const int h = lh0 + i * 8;
    dst[(size_t)h * KK + lk] = tile[lk][h];             // coalesced 256B/wave
  }
}

// ---------------------------------------------------------------------------
// Kernel 2 (v3): two-phase.
// Phase 1: 1 thread = 1 voxel, projection computed ONCE per (voxel,cam);
//          clamped corner offsets (int4) + masked bilinear weights (float4)
//          stored to LDS. Invalid cams (pz<=0) get all-zero weights.
// Phase 2: 8 lanes = 1 voxel cooperative gather (lane j owns k-chunk j, one
//          128B heatmap line per corner), weights/offsets broadcast-read from
//          LDS, per-cam skip when all weights are zero. Output re-transposed
//          through a conflict-free LDS tile for 128B-coalesced stores.
// ---------------------------------------------------------------------------
__global__ __launch_bounds__(256) void unproject3(
    const float* __restrict__ hmT,    // (B,C,H,W,K)
    const float* __restrict__ Pm,     // (B,C,3,4)
    const float* __restrict__ coords, // (B,N,3)
    const float* __restrict__ conf,   // (B,C,K)
    float* __restrict__ out) {        // (B,K,N)
  __shared__ float  sP[CC * 12];
  __shared__ float  sConf[CC][KK];
  __shared__ int4   sOff[CC][256];    // 16 KB
  __shared__ float4 sW[CC][256];      // 16 KB
  __shared__ float  vtile[32][KK + 1];

  const int t     = threadIdx.x;
  const int vbase = blockIdx.x * 256;     // global voxel base (b*N + n)
  const int b     = vbase >> 18;          // uniform per block
  const int nbase = vbase & (NN - 1);

  if (t < CC * 12) sP[t] = Pm[b * CC * 12 + t];
  if (t < KK) {
    const float c0 = conf[(b * CC + 0) * KK + t];
    const float c1 = conf[(b * CC + 1) * KK + t];
    const float c2 = conf[(b * CC + 2) * KK + t];
    const float c3 = conf[(b * CC + 3) * KK + t];
    const float s  = c0 + c1 + c2 + c3;
    sConf[0][t] = c0 / s;
    sConf[1][t] = c1 / s;
    sConf[2][t] = c2 / s;
    sConf[3][t] = c3 / s;
  }
  __syncthreads();

  // ---- Phase 1: projection for my voxel ----------------------------------
  {
    const float x = coords[(size_t)(vbase + t) * 3 + 0];
    const float y = coords[(size_t)(vbase + t) * 3 + 1];
    const float z = coords[(size_t)(vbase + t) * 3 + 2];
    // ix = (gx+1)*0.5*(W-1) with gx = 2*(u/H-0.5)  =>  ix = u*(W-1)/H
    const float sxc = (float)(WWW - 1) / (float)HHH;
    const float syc = (float)(HHH - 1) / (float)WWW;
#pragma unroll
    for (int c = 0; c < CC; ++c) {
      const float* P = &sP[c * 12];
      const float pz = P[8] * x + P[9] * y + P[10] * z + P[11];
      const float valid = (pz > 0.0f) ? 1.0f : 0.0f;
      const float zs    = (pz > 0.0f) ? pz : 1.0f;   // no inf/NaN ever
      const float px = P[0] * x + P[1] * y + P[2] * z + P[3];
      const float py = P[4] * x + P[5] * y + P[6] * z + P[7];
      const float u = px / zs, v2 = py / zs;
      const float ix = u * sxc, iy = v2 * syc;
      const float x0f = floorf(ix), y0f = floorf(iy);
      const float x1f = x0f + 1.0f, y1f = y0f + 1.0f;
      const float wx1 = ix - x0f, wx0 = 1.0f - wx1;
      const float wy1 = iy - y0f, wy0 = 1.0f - wy1;
      const float ibx0 = (x0f >= 0.f && x0f <= (float)(WWW - 1)) ? 1.f : 0.f;
      const float ibx1 = (x1f >= 0.f && x1f <= (float)(WWW - 1)) ? 1.f : 0.f;
      const float iby0 = (y0f >= 0.f && y0f <= (float)(HHH - 1)) ? 1.f : 0.f;
      const float iby1 = (y1f >= 0.f && y1f <= (float)(HHH - 1)) ? 1.f : 0.f;
      const int x0i = (int)fminf(fmaxf(x0f, 0.f), (float)(WWW - 1));
      const int x1i = (int)fminf(fmaxf(x1f, 0.f), (float)(WWW - 1));
      const int y0i = (int)fminf(fmaxf(y0f, 0.f), (float)(HHH - 1));
      const int y1i = (int)fminf(fmaxf(y1f, 0.f), (float)(HHH - 1));
      sOff[c][t] = make_int4(y0i * WWW + x0i, y0i * WWW + x1i,
                             y1i * WWW + x0i, y1i * WWW + x1i);
      sW[c][t] = make_float4(wx0 * wy0 * (ibx0 * iby0 * valid),
                             wx1 * wy0 * (ibx1 * iby0 * valid),
                             wx0 * wy1 * (ibx0 * iby1 * valid),
                             wx1 * wy1 * (ibx1 * iby1 * valid));
    }
  }
  __syncthreads();

  // ---- Phase 2: cooperative gather ---------------------------------------
  const int vloc = t >> 3;                // voxel-within-pass (0..31)
  const int j    = t & 7;                 // k-chunk (k = 4j..4j+3)

  float4 cf[CC];
#pragma unroll
  for (int c = 0; c < CC; ++c) cf[c] = ((const float4*)sConf[c])[j];

  const float* base0 = hmT + (size_t)b * CC * HWSZ * KK + j * 4;
  float* ob = out + (size_t)b * KK * NN + nbase;

  for (int pass = 0; pass < 8; ++pass) {
    const int v = pass * 32 + vloc;
    float4 acc = make_float4(0.f, 0.f, 0.f, 0.f);
#pragma unroll
    for (int c = 0; c < CC; ++c) {
      const float4 w = sW[c][v];          // broadcast across the 8 lanes
      if (w.x + w.y + w.z + w.w > 0.0f) {
        const int4 off = sOff[c][v];
        const float* bc = base0 + (size_t)c * HWSZ * KK;
        const float4 g00 = *(const float4*)(bc + (size_t)off.x * KK);
        const float4 g01 = *(const float4*)(bc + (size_t)off.y * KK);
        const float4 g10 = *(const float4*)(bc + (size_t)off.z * KK);
        const float4 g11 = *(const float4*)(bc + (size_t)off.w * KK);
        acc.x += (g00.x * w.x + g01.x * w.y + g10.x * w.z + g11.x * w.w) * cf[c].x;
        acc.y += (g00.y * w.x + g01.y * w.y + g10.y * w.z + g11.y * w.w) * cf[c].y;
        acc.z += (g00.z * w.x + g01.z * w.y + g10.z * w.z + g11.z * w.w) * cf[c].z;
        acc.w += (g00.w * w.x + g01.w * w.y + g10.w * w.z + g11.w * w.w) * cf[c].w;
      }
    }
    vtile[vloc][j * 4 + 0] = acc.x;
    vtile[vloc][j * 4 + 1] = acc.y;
    vtile[vloc][j * 4 + 2] = acc.z;
    vtile[vloc][j * 4 + 3] = acc.w;
    __syncthreads();
#pragma unroll
    for (int q = 0; q < 4; ++q) {
      const int idx = t + q * 256;
      const int k   = idx >> 5;
      const int n0  = idx & 31;
      ob[(size_t)k * NN + pass * 32 + n0] = vtile[n0][k];  // 2x128B per wave
    }
    __syncthreads();
  }
}

// ---------------------------------------------------------------------------
// Fallback (native layout, no workspace): one thread = one voxel, strided k.
// ---------------------------------------------------------------------------
__global__ __launch_bounds__(256) void unproject_native(
    const float* __restrict__ hm, const float* __restrict__ Pm,
    const float* __restrict__ coords, const float* __restrict__ conf,
    float* __restrict__ out) {
  __shared__ float sP[CC * 12];
  __shared__ float sConf[CC * KK];
  const int t   = threadIdx.x;
  const int gid = blockIdx.x * 256 + t;
  const int b   = gid >> 18;
  const int n   = gid & (NN - 1);
  if (t < CC * 12) sP[t] = Pm[b * CC * 12 + t];
  if (t < KK) {
    const float c0 = conf[(b * CC + 0) * KK + t];
    const float c1 = conf[(b * CC + 1) * KK + t];
    const float c2 = conf[(b * CC + 2) * KK + t];
    const float c3 = conf[(b * CC + 3) * KK + t];
    const float s  = c0 + c1 + c2 + c3;
    sConf[0 * KK + t] = c0 / s; sConf[1 * KK + t] = c1 / s;
    sConf[2 * KK + t] = c2 / s; sConf[3 * KK + t] = c3 / s;
  }
  __syncthreads();
  const float x = coords[(size_t)gid * 3 + 0];
  const float y = coords[(size_t)gid * 3 + 1];
  const float z = coords[(size_t)gid * 3 + 2];
  float accs[KK];
#pragma unroll
  for (int k = 0; k < KK; ++k) accs[k] = 0.f;
  const float sxc = (float)(WWW - 1) / (float)HHH;
  const float syc = (float)(HHH - 1) / (float)WWW;
#pragma unroll
  for (int c = 0; c < CC; ++c) {
    const float* P = &sP[c * 12];
    const float pz = P[8] * x + P[9] * y + P[10] * z + P[11];
    if (pz > 0.0f) {
      const float px = P[0] * x + P[1] * y + P[2] * z + P[3];
      const float py = P[4] * x + P[5] * y + P[6] * z + P[7];
      const float u = px / pz, v2 = py / pz;
      const float ix = u * sxc, iy = v2 * syc;
      const float x0f = floorf(ix), y0f = floorf(iy);
      const float x1f = x0f + 1.0f, y1f = y0f + 1.0f;
      const float wx1 = ix - x0f, wx0 = 1.0f - wx1;
      const float wy1 = iy - y0f, wy0 = 1.0f - wy1;
      const float ibx0 = (x0f >= 0.f && x0f <= (float)(WWW - 1)) ? 1.f : 0.f;
      const float ibx1 = (x1f >= 0.f && x1f <= (float)(WWW - 1)) ? 1.f : 0.f;
      const float iby0 = (y0f >= 0.f && y0f <= (float)(HHH - 1)) ? 1.f : 0.f;
      const float iby1 = (y1f >= 0.f && y1f <= (float)(HHH - 1)) ? 1.f : 0.f;
      const float w00 = wx0 * wy0 * ibx0 * iby0;
      const float w01 = wx1 * wy0 * ibx1 * iby0;
      const float w10 = wx0 * wy1 * ibx0 * iby1;
      const float w11 = wx1 * wy1 * ibx1 * iby1;
      const int x0i = (int)fminf(fmaxf(x0f, 0.f), (float)(WWW - 1));
      const int x1i = (int)fminf(fmaxf(x1f, 0.f), (float)(WWW - 1));
      const int y0i = (int)fminf(fmaxf(y0f, 0.f), (float)(HHH - 1));
      const int y1i = (int)fminf(fmaxf(y1f, 0.f), (float)(HHH - 1));
      const float* bse = hm + (size_t)(b * CC + c) * KK * HWSZ;
      const int i00 = y0i * WWW + x0i, i01 = y0i * WWW + x1i;
      const int i10 = y1i * WWW + x0i, i11 = y1i * WWW + x1i;
#pragma unroll
      for (int k = 0; k < KK; ++k) {
        const float* hk = bse + (size_t)k * HWSZ;
        accs[k] += (hk[i00] * w00 + hk[i01] * w01 +
                    hk[i10] * w10 + hk[i11] * w11) * sConf[c * KK + k];
      }
    }
  }
  float* ob = out + (size_t)b * KK * NN + n;
#pragma unroll
  for (int k = 0; k < KK; ++k) ob[(size_t)k * NN] = accs[k];
}

extern "C" void kernel_launch(void* const* d_in, const int* in_sizes, int n_in,
                              void* d_out, int out_size, void* d_ws, size_t ws_size,
                              hipStream_t stream) {
  const float* heatmaps = (const float*)d_in[0];  // (B,C,K,H,W)
  const float* Pm       = (const float*)d_in[1];  // (B,C,3,4)
  const float* coords   = (const float*)d_in[2];  // (B,D,D,D,3)
  const float* conf     = (const float*)d_in[3];  // (B,C,K)
  float* out            = (float*)d_out;          // (B,K,D,D,D)

  const size_t hmT_bytes = (size_t)BB * CC * HWSZ * KK * sizeof(float); // 9.4 MB

  if (ws_size >= hmT_bytes) {
    float* hmT = (float*)d_ws;
    dim3 tg(HWSZ / 64, BB * CC);                  // (144, 8)
    hm_transpose<<<tg, 256, 0, stream>>>(heatmaps, hmT);
    const int grid = (BB * NN) / 256;             // 2048 blocks, 256 voxels each
    unproject3<<<grid, 256, 0, stream>>>(hmT, Pm, coords, conf, out);
  } else {
    const int grid = (BB * NN) / 256;
    unproject_native<<<grid, 256, 0, stream>>>(heatmaps, Pm, coords, conf, out);
  }
}